// Round 4
// baseline (410.207 us; speedup 1.0000x reference)
//
#include <hip/hip_runtime.h>
#include <math.h>

#define NTOK (16 * 8192)   // 131072 tokens
#define H    256
#define E    32
#define SEQ  8192
#define BSZ  16

typedef float f16v __attribute__((ext_vector_type(16)));

// ---------------- zero the workspace accumulators ----------------
__global__ __launch_bounds__(256) void zero_ws_kernel(float* ws) {
    int i = blockIdx.x * 256 + threadIdx.x;
    if (i < BSZ * E * 2) ws[i] = 0.0f;
}

// 16 serial FMAs into one accumulator (dep chain ~4cyc each; independent
// across the 32 expert steps, 2 waves/SIMD hide the rest)
#define FMA16(ACC, WB) \
    { float a_ = (ACC); \
      a_ += WB[0]  * xq0;  a_ += WB[1]  * xq1;  a_ += WB[2]  * xq2;  a_ += WB[3]  * xq3;  \
      a_ += WB[4]  * xq4;  a_ += WB[5]  * xq5;  a_ += WB[6]  * xq6;  a_ += WB[7]  * xq7;  \
      a_ += WB[8]  * xq8;  a_ += WB[9]  * xq9;  a_ += WB[10] * xq10; a_ += WB[11] * xq11; \
      a_ += WB[12] * xq12; a_ += WB[13] * xq13; a_ += WB[14] * xq14; a_ += WB[15] * xq15; \
      (ACC) = a_; }

// One expert step: issue scalar prefetch of the NEXT 64B w block into NXTB,
// 16 FMAs with CURB (already waited), then drain (lgkmcnt(0) is the only safe
// SMEM wait; "+s" tie orders the wait before NXTB's consumers next step).
// e==31 prefetches (hb+1, e=0) at wp+64B (always in-bounds: <= w + 1024B + 960B).
#define WSTEP(E_, CURB, NXTB) \
    asm volatile("s_load_dwordx16 %0, %1, %2" \
                 : "=s"(NXTB) : "s"(wp), "i"((E_) == 31 ? 64 : 1024 * ((E_) + 1))); \
    FMA16(acc[E_], CURB); \
    asm volatile("s_waitcnt lgkmcnt(0)" : "+s"(NXTB));

// ---------------- main gate kernel ----------------
// w streamed through SGPRs via s_load_dwordx16 (scalar pipe, K$): zero LDS,
// zero per-lane VMEM for w. x streamed per-lane (float4 x4, depth-1 dbuf).
// acc[32] + pipeline ~ 80 VGPR -> no spills.
__global__ __launch_bounds__(256, 2) void gate_kernel(
    const float* __restrict__ x, const float* __restrict__ w,
    float* __restrict__ out, float* __restrict__ ws_cnt, float* __restrict__ ws_sum)
{
    const int tid   = threadIdx.x;
    const int token = blockIdx.x * 256 + tid;
    const int lane  = tid & 63;

    float acc[E];
#pragma unroll
    for (int e = 0; e < E; ++e) acc[e] = 0.0f;

    const float* xrow = x + (size_t)token * H;

    // x double-buffer: 16 floats (one h-block) per stage
    float4 cur[4], nxt[4];
#pragma unroll
    for (int j = 0; j < 4; ++j)
        cur[j] = *(const float4*)(xrow + 4 * j);

    // scalar w pipeline: preload (hb=0, e=0)
    const float* wp = w;   // uniform; advances 16 floats per hb
    f16v wA, wB;
    asm volatile("s_load_dwordx16 %0, %1, 0" : "=s"(wA) : "s"(w));
    asm volatile("s_waitcnt lgkmcnt(0)" : "+s"(wA));

#pragma unroll 1
    for (int hb = 0; hb < 16; ++hb) {
        const int hn = ((hb + 1) & 15) * 16;   // wraps (L1-hot, in-bounds)
#pragma unroll
        for (int j = 0; j < 4; ++j)
            nxt[j] = *(const float4*)(xrow + hn + 4 * j);

        const float xq0  = cur[0].x, xq1  = cur[0].y, xq2  = cur[0].z, xq3  = cur[0].w;
        const float xq4  = cur[1].x, xq5  = cur[1].y, xq6  = cur[1].z, xq7  = cur[1].w;
        const float xq8  = cur[2].x, xq9  = cur[2].y, xq10 = cur[2].z, xq11 = cur[2].w;
        const float xq12 = cur[3].x, xq13 = cur[3].y, xq14 = cur[3].z, xq15 = cur[3].w;

        WSTEP( 0, wA, wB) WSTEP( 1, wB, wA) WSTEP( 2, wA, wB) WSTEP( 3, wB, wA)
        WSTEP( 4, wA, wB) WSTEP( 5, wB, wA) WSTEP( 6, wA, wB) WSTEP( 7, wB, wA)
        WSTEP( 8, wA, wB) WSTEP( 9, wB, wA) WSTEP(10, wA, wB) WSTEP(11, wB, wA)
        WSTEP(12, wA, wB) WSTEP(13, wB, wA) WSTEP(14, wA, wB) WSTEP(15, wB, wA)
        WSTEP(16, wA, wB) WSTEP(17, wB, wA) WSTEP(18, wA, wB) WSTEP(19, wB, wA)
        WSTEP(20, wA, wB) WSTEP(21, wB, wA) WSTEP(22, wA, wB) WSTEP(23, wB, wA)
        WSTEP(24, wA, wB) WSTEP(25, wB, wA) WSTEP(26, wA, wB) WSTEP(27, wB, wA)
        WSTEP(28, wA, wB) WSTEP(29, wB, wA) WSTEP(30, wA, wB) WSTEP(31, wB, wA)
        // after e=31: wA holds (hb+1, e=0) -> loop invariant maintained

        wp += 16;
#pragma unroll
        for (int j = 0; j < 4; ++j) cur[j] = nxt[j];
    }

    // ---- argmax (first occurrence wins) + softmax denom ----
    float m = acc[0];
    int   idx = 0;
#pragma unroll
    for (int e = 1; e < E; ++e) {
        if (acc[e] > m) { m = acc[e]; idx = e; }
    }
    float sc[E];
    float ssum = 0.0f;
#pragma unroll
    for (int e = 0; e < E; ++e) {
        sc[e] = expf(acc[e] - m);
        ssum += sc[e];
    }
    const float inv = 1.0f / ssum;   // softmax score at argmax; SCALING = 1.0

    out[token]        = (float)idx;
    out[NTOK + token] = inv;

    // ---- per-(batch, expert) accumulation for aux loss ----
    const int b = token >> 13;  // /SEQ, wave-uniform

#pragma unroll 1
    for (int e = 0; e < E; ++e) {
        unsigned long long ball = __ballot(idx == e);
        if (lane == 0 && ball)
            atomicAdd(&ws_cnt[b * E + e], (float)__popcll(ball));
        float v = sc[e] * inv;
#pragma unroll
        for (int off = 32; off > 0; off >>= 1)
            v += __shfl_xor(v, off, 64);
        if (lane == 0)
            atomicAdd(&ws_sum[b * E + e], v);
    }
}

// ---------------- aux loss reduction ----------------
__global__ __launch_bounds__(256) void aux_kernel(
    const float* __restrict__ ws_cnt, const float* __restrict__ ws_sum,
    float* __restrict__ out)
{
    const int tid = threadIdx.x;
    float p = 0.0f;
    for (int i = tid; i < BSZ * E; i += 256)
        p += ws_cnt[i] * ws_sum[i];

    __shared__ float red[4];
#pragma unroll
    for (int off = 32; off > 0; off >>= 1)
        p += __shfl_xor(p, off, 64);
    if ((tid & 63) == 0) red[tid >> 6] = p;
    __syncthreads();
    if (tid == 0) {
        float t = red[0] + red[1] + red[2] + red[3];
        // aux = sum_be cnt*ssum * alpha / (B * (SEQ/E) * SEQ)
        out[2 * NTOK] = t * (0.001f / (16.0f * 256.0f * 8192.0f));
    }
}

extern "C" void kernel_launch(void* const* d_in, const int* in_sizes, int n_in,
                              void* d_out, int out_size, void* d_ws, size_t ws_size,
                              hipStream_t stream) {
    const float* x = (const float*)d_in[0];
    const float* w = (const float*)d_in[1];
    float* out    = (float*)d_out;
    float* ws     = (float*)d_ws;
    float* ws_cnt = ws;
    float* ws_sum = ws + BSZ * E;

    zero_ws_kernel<<<4, 256, 0, stream>>>(ws);
    gate_kernel<<<NTOK / 256, 256, 0, stream>>>(x, w, out, ws_cnt, ws_sum);
    aux_kernel<<<1, 256, 0, stream>>>(ws_cnt, ws_sum, out);
}

// Round 5
// 296.962 us; speedup vs baseline: 1.3813x; 1.3813x over previous
//
#include <hip/hip_runtime.h>
#include <math.h>

#define NTOK (16 * 8192)   // 131072 tokens
#define H    256
#define E    32
#define SEQ  8192
#define BSZ  16
#define TOKB 64            // tokens per block
#define NCH  16            // h-chunks of 16 floats

// ---------------- zero the workspace accumulators ----------------
__global__ __launch_bounds__(256) void zero_ws_kernel(float* ws) {
    int i = blockIdx.x * 256 + threadIdx.x;
    if (i < BSZ * E * 2) ws[i] = 0.0f;
}

// ---------------- main gate kernel ----------------
// Block: 256 thr = 4 waves = 4 expert-groups (8 experts each), 64 tokens.
// Wave lanes: tg = lane&15 (4 tokens each), hq = lane>>4 (4-float h-slice of
// each 16-float chunk). Per chunk/thread: 4 x-reads + 8 w-reads -> 128 FMAs.
// acc[4][8]=32 VGPR. h-quarters merged via shfl_xor(16,32); expert-groups
// merged via LDS (m, s, idx) online-softmax combine.
__global__ __launch_bounds__(256, 4) void gate_kernel(
    const float* __restrict__ x, const float* __restrict__ w,
    float* __restrict__ out, float* __restrict__ ws_cnt, float* __restrict__ ws_sum)
{
    __shared__ float  w_lds[E * H];     // 32 KB
    __shared__ float4 xb4[2][256];      // 2 x 4 KB x-chunk dbuf (epilogue overlays)

    const int tid  = threadIdx.x;
    const int lane = tid & 63;
    const int eg   = tid >> 6;          // wave id = expert group
    const int tg   = lane & 15;         // token group (4 tokens)
    const int hq   = lane >> 4;         // h-quarter within chunk

    const int blkbase = blockIdx.x * TOKB;

    // ---- stage w into LDS (one-time, coalesced float4) ----
    {
        const float4* wg = (const float4*)w;
        float4*       wl = (float4*)w_lds;
#pragma unroll
        for (int i = 0; i < 8; ++i) wl[tid + 256 * i] = wg[tid + 256 * i];
    }

    // ---- x chunk prefetch: thread stages one float4 per chunk ----
    const int s_tok = tid >> 2, s_part = tid & 3;
    const float* gsrc = x + (size_t)(blkbase + s_tok) * H + s_part * 4;
    float4 v = *(const float4*)gsrc;    // chunk 0

    float acc[4][8];
#pragma unroll
    for (int t = 0; t < 4; ++t)
#pragma unroll
        for (int e = 0; e < 8; ++e) acc[t][e] = 0.0f;

#pragma unroll 1
    for (int kc = 0; kc < NCH; ++kc) {
        xb4[kc & 1][tid] = v;                                   // store chunk kc
        if (kc < NCH - 1) v = *(const float4*)(gsrc + (kc + 1) * 16);  // prefetch
        __syncthreads();                                        // chunk visible

        const float* xc = (const float*)xb4[kc & 1];
        float4 xf[4];
#pragma unroll
        for (int t = 0; t < 4; ++t)
            xf[t] = *(const float4*)(xc + (tg * 4 + t) * 16 + hq * 4);

#pragma unroll
        for (int e = 0; e < 8; ++e) {
            const float4 wf = *(const float4*)(w_lds + (eg * 8 + e) * H + kc * 16 + hq * 4);
#pragma unroll
            for (int t = 0; t < 4; ++t)
                acc[t][e] += wf.x * xf[t].x + wf.y * xf[t].y
                           + wf.z * xf[t].z + wf.w * xf[t].w;
        }
        // single barrier per iter is sufficient: next overwrite of this buffer
        // (iter kc+2's store) is ordered behind iter kc+1's barrier.
    }
    __syncthreads();   // k-loop fully done before overlaying xb4

    // ---- merge h-quarters: all lanes end with full logits for 4 tokens ----
#pragma unroll
    for (int t = 0; t < 4; ++t)
#pragma unroll
        for (int e = 0; e < 8; ++e) {
            acc[t][e] += __shfl_xor(acc[t][e], 16, 64);
            acc[t][e] += __shfl_xor(acc[t][e], 32, 64);
        }

    // ---- phase A: each lane finalizes token etok = tg*4+hq for its 8 experts
    const int etok = tg * 4 + hq;
    float l[8];
#pragma unroll
    for (int e = 0; e < 8; ++e)
        l[e] = hq == 0 ? acc[0][e] : (hq == 1 ? acc[1][e] : (hq == 2 ? acc[2][e] : acc[3][e]));

    float m8 = l[0];
    int   i8 = 0;
#pragma unroll
    for (int e = 1; e < 8; ++e)
        if (l[e] > m8) { m8 = l[e]; i8 = e; }
    float s8 = 0.0f;
#pragma unroll
    for (int e = 0; e < 8; ++e) s8 += expf(l[e] - m8);

    float4* pm = (float4*)xb4;                       // [eg*64+tok] (m, s, idx, 0)
    float2* mi = (float2*)((float*)xb4 + 1024);      // [tok] (M, inv)
    pm[eg * 64 + etok] = make_float4(m8, s8, (float)(eg * 8 + i8), 0.0f);
    __syncthreads();

    // ---- phase B: wave 0 merges the 4 expert-groups, writes outputs ----
    if (tid < 64) {
        const int tok = tid;
        float4 p[4];
#pragma unroll
        for (int g = 0; g < 4; ++g) p[g] = pm[g * 64 + tok];

        float M = p[0].x, idxf = p[0].z;
#pragma unroll
        for (int g = 1; g < 4; ++g)
            if (p[g].x > M) { M = p[g].x; idxf = p[g].z; }
        float S = 0.0f;
#pragma unroll
        for (int g = 0; g < 4; ++g) S += p[g].y * expf(p[g].x - M);
        const float inv = 1.0f / S;    // winner's softmax score; SCALING = 1.0

        const int T = blkbase + tok;
        out[T]        = idxf;
        out[NTOK + T] = inv;
        mi[tok] = make_float2(M, inv);

        // expert-selection counts (wave 0 fully active -> ballot safe)
        const int IDX = (int)idxf;
        const int b   = T >> 13;       // /SEQ, uniform
#pragma unroll 1
        for (int e = 0; e < E; ++e) {
            unsigned long long ball = __ballot(IDX == e);
            if (lane == 0 && ball)
                atomicAdd(&ws_cnt[b * E + e], (float)__popcll(ball));
        }
    }
    __syncthreads();

    // ---- phase C: score sums per (batch, expert) ----
    {
        const float2 p = mi[etok];
        const int b = blkbase >> 13;   // uniform
#pragma unroll 1
        for (int e = 0; e < 8; ++e) {
            float sc = expf(l[e] - p.x) * p.y;
#pragma unroll
            for (int off = 32; off > 0; off >>= 1)
                sc += __shfl_xor(sc, off, 64);
            if (lane == 0)
                atomicAdd(&ws_sum[b * E + eg * 8 + e], sc);
        }
    }
}

// ---------------- aux loss reduction ----------------
__global__ __launch_bounds__(256) void aux_kernel(
    const float* __restrict__ ws_cnt, const float* __restrict__ ws_sum,
    float* __restrict__ out)
{
    const int tid = threadIdx.x;
    float p = 0.0f;
    for (int i = tid; i < BSZ * E; i += 256)
        p += ws_cnt[i] * ws_sum[i];

    __shared__ float red[4];
#pragma unroll
    for (int off = 32; off > 0; off >>= 1)
        p += __shfl_xor(p, off, 64);
    if ((tid & 63) == 0) red[tid >> 6] = p;
    __syncthreads();
    if (tid == 0) {
        float t = red[0] + red[1] + red[2] + red[3];
        // aux = sum_be cnt*ssum * alpha / (B * (SEQ/E) * SEQ)
        out[2 * NTOK] = t * (0.001f / (16.0f * 256.0f * 8192.0f));
    }
}

extern "C" void kernel_launch(void* const* d_in, const int* in_sizes, int n_in,
                              void* d_out, int out_size, void* d_ws, size_t ws_size,
                              hipStream_t stream) {
    const float* x = (const float*)d_in[0];
    const float* w = (const float*)d_in[1];
    float* out    = (float*)d_out;
    float* ws     = (float*)d_ws;
    float* ws_cnt = ws;
    float* ws_sum = ws + BSZ * E;

    zero_ws_kernel<<<4, 256, 0, stream>>>(ws);
    gate_kernel<<<NTOK / TOKB, 256, 0, stream>>>(x, w, out, ws_cnt, ws_sum);
    aux_kernel<<<1, 256, 0, stream>>>(ws_cnt, ws_sum, out);
}